// Round 12
// baseline (227.746 us; speedup 1.0000x reference)
//
#include <hip/hip_runtime.h>

// Causal GQA prefill attention, flash-style, bf16 MFMA / fp32 softmax.
// B=2, S=2048, H=32, HKV=8, D=128, G=4.
// Prepass (fused, 1 launch): K fp32->bf16 (k-row use) and V -> Vt.
// Round 11: in-register P at (256,4) -> attn 114 us, total 223 (best).
//   Ledger model: wall*waves ~ const -> regs cap TLP at 16 waves/CU;
//   remaining lever = shorten per-wave chain per iteration.
// Round 12 (this): PIPELINE QK^T one tile ahead (T15 mechanism):
//   iter i: stage(i+1); QK^T(i)+mask -> scNEW; softmax+PV(i-1) on
//   scOLD; barrier. QK^T MFMAs (matrix pipe) overlap prev-tile softmax
//   (VALU/trans pipes). KL dbuf by parity; VL TRIPLE-buffered (i mod 3)
//   since PV trails staging by 2 tiles. LDS 40 KB -> still 4 blocks/CU.
//   sc doubled (scA/scB, literal roles via unroll-2). Extra phase-seal
//   barrier (pipe epilogue reads VL after last loop barrier).

#define B_   2
#define S_   2048
#define H_   32
#define HKV_ 8
#define D_   128
#define SCALEF 0.08838834764831845f
#define COEF  (SCALEF * 1.44269504088896340736f)   // scale * log2(e)
#define DEFER_THR 8.0f                             // log2-domain defer-max

typedef float          f32x4 __attribute__((ext_vector_type(4)));
typedef __bf16         bf16x4 __attribute__((ext_vector_type(4)));
typedef __bf16         bf16x8 __attribute__((ext_vector_type(8)));
typedef unsigned short u16x8 __attribute__((ext_vector_type(8)));

#define MFMA16(a, b, c) __builtin_amdgcn_mfma_f32_16x16x32_bf16((a), (b), (c), 0, 0, 0)

#if defined(__has_builtin)
#if __has_builtin(__builtin_amdgcn_exp2f)
#define EXP2F(x) __builtin_amdgcn_exp2f(x)
#endif
#endif
#ifndef EXP2F
#define EXP2F(x) exp2f(x)
#endif

static __device__ __forceinline__ unsigned short f2bf(float f) {
  unsigned int u = __builtin_bit_cast(unsigned int, f);
  u = (u + 0x7fffu + ((u >> 16) & 1u)) >> 16;   // RNE; inputs finite
  return (unsigned short)u;
}

// async global->LDS, 16B per lane; lds dest = wave-uniform base + lane*16.
static __device__ __forceinline__ void load_lds16(const void* g, void* l) {
  __builtin_amdgcn_global_load_lds(
      (const __attribute__((address_space(1))) void*)g,
      (__attribute__((address_space(3))) void*)l, 16, 0, 0);
}

// lane^16 exchange (DS pipe, within 32-lane halves): BitMode xor=16.
static __device__ __forceinline__ float swz_x16(float v) {
  return __builtin_bit_cast(
      float, __builtin_amdgcn_ds_swizzle(__builtin_bit_cast(int, v), 0x401F));
}
// generic pull from lane (byteaddr/4): full 64-lane crossbar.
static __device__ __forceinline__ float bperm_f(int byteaddr, float v) {
  return __builtin_bit_cast(
      float,
      __builtin_amdgcn_ds_bpermute(byteaddr, __builtin_bit_cast(int, v)));
}

// ------------- Fused prepass: blocks 0..2047 convert K, 2048..4095
// transpose V. Independent work -> concurrent, one launch. -------------
__global__ __launch_bounds__(256) void prep_kernel(
    const float* __restrict__ k, const float* __restrict__ v,
    unsigned short* __restrict__ kbf, unsigned short* __restrict__ vt) {
  __shared__ float tile[32][65];  // +1 pad: conflict-free (V branch only)
  const int tid = threadIdx.x;
  const int gid = (int)blockIdx.x;
  if (gid < 2048) {
    // ---- K fp32 -> bf16 [b][hkv][S][D] ----
    int t = gid * 256 + tid;
    int o = t * 8;                       // output-linear index
    int d = o & (D_ - 1);
    int s = (o >> 7) & (S_ - 1);
    int bh = o >> 18;                    // 0..15
    int b = bh >> 3, hkv = bh & 7;
    const float* src = k + (size_t)(b * S_ + s) * (HKV_ * D_) + hkv * D_ + d;
    f32x4 x0 = *(const f32x4*)src;
    f32x4 x1 = *(const f32x4*)(src + 4);
    u16x8 w;
    w[0] = f2bf(x0[0]); w[1] = f2bf(x0[1]); w[2] = f2bf(x0[2]); w[3] = f2bf(x0[3]);
    w[4] = f2bf(x1[0]); w[5] = f2bf(x1[1]); w[6] = f2bf(x1[2]); w[7] = f2bf(x1[3]);
    *(u16x8*)(kbf + o) = w;
  } else {
    // ---- V -> Vt (bf16, [b][hkv][D][S]) ----
    const int t = gid - 2048;
    const int s0 = (t & 31) * 64;        // 32 s-tiles
    const int d0 = ((t >> 5) & 3) * 32;  // 4 d-tiles
    const int bh = t >> 7;               // 16 (b*8+hkv)
    const float* src = v + (size_t)(bh >> 3) * S_ * (HKV_ * D_) + (bh & 7) * D_;
#pragma unroll
    for (int it = 0; it < 8; ++it) {
      int idx = it * 256 + tid;
      int sl = idx >> 5, dl = idx & 31;  // coalesced along d
      tile[dl][sl] = src[(size_t)(s0 + sl) * (HKV_ * D_) + d0 + dl];
    }
    __syncthreads();
    unsigned int* dst = (unsigned int*)vt;
#pragma unroll
    for (int it = 0; it < 4; ++it) {
      int idx = it * 256 + tid;
      int dl = idx >> 5, sp = idx & 31;
      unsigned int w = (unsigned int)f2bf(tile[dl][2 * sp]) |
                       ((unsigned int)f2bf(tile[dl][2 * sp + 1]) << 16);
      dst[(((size_t)bh * D_ + d0 + dl) * S_ + s0 + 2 * sp) >> 1] = w;
    }
  }
}

// ------------- Main attention kernel -------------
__global__ __launch_bounds__(256, 4) void attn_kernel(
    const float* __restrict__ qg, const unsigned short* __restrict__ kbfg,
    const unsigned short* __restrict__ vtg, float* __restrict__ outg) {
  __shared__ unsigned short KL[2][32 * 128];   // 2 x 8 KB (k-row permuted)
  __shared__ unsigned short VL[3][128 * 32];   // 3 x 8 KB (chunk-swizzled)
  // total LDS = 40960 B -> 4 blocks/CU (160 KiB pool exactly)

  const int tid = threadIdx.x;
  const int wave = tid >> 6, lane = tid & 63;
  const int l15 = lane & 15, quad = lane >> 4;
  const int a32 = ((lane ^ 32) << 2);  // bpermute addr: lane+-32 partner
  const int rowa = quad << 4;          // bpermute addr base: row quad*4

  // XCD-locality remap: dispatch id round-robins xcd = id&7 (8 XCDs).
  const int id = (int)blockIdx.x + 16 * (int)blockIdx.y;  // 0..1023
  const int xcd = id & 7, slot = id >> 3;                 // slot 0..127
  const int bhkv = xcd * 2 + (slot >> 6);
  const int inner = slot & 63;
  const int g = inner >> 4;         // 0..3 head-in-group
  const int xb = inner & 15;        // causal pair index
  const int b = bhkv >> 3, hkv = bhkv & 7;
  const int h = hkv * 4 + g;

  const unsigned short* kbf = kbfg + (size_t)(b * HKV_ + hkv) * S_ * D_;
  const unsigned short* vtb = vtg + (size_t)(b * HKV_ + hkv) * D_ * S_;

  const f32x4 zero4 = {0.f, 0.f, 0.f, 0.f};
  const float NEG_INF = -__builtin_huge_valf();

  // ---- async staging of one K/Vt tile pair ----
  // K ROW PERMUTATION: LDS row kr = h2*16+i holds global k-row
  //   gs = (i>>2)*8 + h2*4 + (i&3)  (makes P lane-local for PV).
  // K chunk swizzle: phys chunk pc of row kr holds logical pc^(kr&15).
  // V chunk swizzle: phys chunk pc of row dr holds logical pc^((dr>>1)&3).
  auto stage = [&](int kt, int kbuf, int vbuf) {
#pragma unroll
    for (int j = 0; j < 2; ++j) {
      int si = wave * 128 + j * 64 + lane;
      int kr = si >> 4, pc = si & 15;
      int lc = pc ^ (kr & 15);
      int gs = ((kr & 15) >> 2) * 8 + ((kr >> 4) << 2) + (kr & 3);
      load_lds16(kbf + (size_t)(kt * 32 + gs) * D_ + lc * 8,
                 &KL[kbuf][(wave * 128 + j * 64) * 8]);
    }
#pragma unroll
    for (int j = 0; j < 2; ++j) {
      int si = wave * 128 + j * 64 + lane;
      int dr = si >> 2, pc = si & 3;
      int lc = pc ^ ((dr >> 1) & 3);
      load_lds16(vtb + (size_t)dr * S_ + kt * 32 + lc * 8,
                 &VL[vbuf][(wave * 128 + j * 64) * 8]);
    }
  };

  for (int ph = 0; ph < 2; ++ph) {
    const int qb = ph ? (31 - xb) : xb;
    const int qbase = qb * 64 + wave * 16;  // this wave's 16 q rows
    const int qgp = qbase + l15;            // this lane's q-row (swapped C)

    // Phase seal: prior phase's pipe epilogue read VL after its last
    // barrier; all waves must pass here before stage(0) overwrites.
    __syncthreads();
    stage(0, 0, 0);

    // Q fragments (A/B-layout identical), pre-scaled by COEF; these
    // global loads overlap the prologue stage.
    bf16x8 qf[4];
#pragma unroll
    for (int ch = 0; ch < 4; ++ch) {
      const float* p = qg + (size_t)(b * S_ + qbase + l15) * (H_ * D_) +
                       h * D_ + ch * 32 + quad * 8;
      f32x4 x0 = *(const f32x4*)p;
      f32x4 x1 = *(const f32x4*)(p + 4);
      bf16x8 t;
      t[0] = (__bf16)(x0[0] * COEF); t[1] = (__bf16)(x0[1] * COEF);
      t[2] = (__bf16)(x0[2] * COEF); t[3] = (__bf16)(x0[3] * COEF);
      t[4] = (__bf16)(x1[0] * COEF); t[5] = (__bf16)(x1[1] * COEF);
      t[6] = (__bf16)(x1[2] * COEF); t[7] = (__bf16)(x1[3] * COEF);
      qf[ch] = t;
    }

    f32x4 acc[8];
#pragma unroll
    for (int dt = 0; dt < 8; ++dt) acc[dt] = zero4;
    float mrow = NEG_INF;  // running max of row q=l15 (scalar)
    float lsum = 0.f;      // lane-partial sum of row q=l15 over own k-cols

    const int nkt = qb * 2 + 2;  // always even, >= 2

    f32x4 scA[2], scB[2];
    int gprev = 0;                       // tile i-1 computed?
    int vprev = 2, vcur = 0, vstage = 1; // VL bufs: (i-1)%3, i%3, (i+1)%3

    __syncthreads();  // drains vmcnt: tile 0 resident

// softmax + PV for the PREVIOUS tile (sc = its scores, VL[vprev] = its V).
#define SOFTPV(SC)                                                            \
  do {                                                                        \
    float l8 = fmaxf(fmaxf(fmaxf(SC[0][0], SC[0][1]),                         \
                           fmaxf(SC[0][2], SC[0][3])),                        \
                     fmaxf(fmaxf(SC[1][0], SC[1][1]),                         \
                           fmaxf(SC[1][2], SC[1][3])));                       \
    if (!__all(l8 <= mrow + DEFER_THR)) {                                     \
      float t = fmaxf(l8, swz_x16(l8));  /* cross-quad row max */             \
      t = fmaxf(t, bperm_f(a32, t));                                          \
      float mn = fmaxf(mrow, t);                                              \
      float al = EXP2F(mrow - mn);                                            \
      mrow = mn;                                                              \
      lsum *= al;                                                             \
      f32x4 av; /* alpha for acc rows quad*4+r, from lanes r' = row */        \
      _Pragma("unroll") for (int r = 0; r < 4; ++r)                           \
          av[r] = bperm_f(rowa + (r << 2), al);                               \
      _Pragma("unroll") for (int dt = 0; dt < 8; ++dt)                        \
          _Pragma("unroll") for (int r = 0; r < 4; ++r)                       \
              acc[dt][r] *= av[r];                                            \
    }                                                                         \
    _Pragma("unroll") for (int h2 = 0; h2 < 2; ++h2)                          \
        _Pragma("unroll") for (int r = 0; r < 4; ++r)                         \
            SC[h2][r] = EXP2F(SC[h2][r] - mrow);                              \
    lsum += ((SC[0][0] + SC[0][1]) + (SC[0][2] + SC[0][3])) +                 \
            ((SC[1][0] + SC[1][1]) + (SC[1][2] + SC[1][3]));                  \
    bf16x8 pb; /* PV A-fragment: pure register casts (cvt_pk) */              \
    pb[0] = (__bf16)SC[0][0]; pb[1] = (__bf16)SC[0][1];                       \
    pb[2] = (__bf16)SC[0][2]; pb[3] = (__bf16)SC[0][3];                       \
    pb[4] = (__bf16)SC[1][0]; pb[5] = (__bf16)SC[1][1];                       \
    pb[6] = (__bf16)SC[1][2]; pb[7] = (__bf16)SC[1][3];                       \
    {                                                                         \
      const unsigned short* vb_ = &VL[vprev][0];                              \
      const int vsw = (quad ^ ((l15 >> 1) & 3)) * 8;  /* un-swizzle V */      \
      __builtin_amdgcn_s_setprio(1);                                          \
      _Pragma("unroll") for (int dt = 0; dt < 8; ++dt) {                      \
        u16x8 vf = *(const u16x8*)&vb_[(dt * 16 + l15) * 32 + vsw];           \
        acc[dt] = MFMA16(pb, __builtin_bit_cast(bf16x8, vf), acc[dt]);        \
      }                                                                       \
      __builtin_amdgcn_s_setprio(0);                                          \
    }                                                                         \
  } while (0)

// One pipelined iteration. PAR = KT&1 (literal): KL buffer + sc role.
// QK^T(KT) -> SCN; softmax+PV(KT-1) on SCO; then barrier.
#define PIPE(KT, PAR, SCN, SCO)                                               \
  do {                                                                        \
    const int kt_ = (KT);                                                     \
    if (kt_ + 1 < nkt) stage(kt_ + 1, (PAR) ^ 1, vstage);                     \
    const int gcur = (kt_ * 32 <= qbase + 15) ? 1 : 0;                        \
    if (gcur) {                                                               \
      SCN[0] = zero4; SCN[1] = zero4;                                         \
      __builtin_amdgcn_s_setprio(1);                                          \
      _Pragma("unroll") for (int h2 = 0; h2 < 2; ++h2) {                      \
        const int row = h2 * 16 + l15;                                        \
        _Pragma("unroll") for (int ch = 0; ch < 4; ++ch) {                    \
          const int pc = (ch * 4 + quad) ^ l15; /* un-swizzle */              \
          u16x8 kf = *(const u16x8*)&KL[(PAR)][row * D_ + pc * 8];            \
          SCN[h2] = MFMA16(__builtin_bit_cast(bf16x8, kf), qf[ch], SCN[h2]);  \
        }                                                                     \
      }                                                                       \
      __builtin_amdgcn_s_setprio(0);                                          \
      const int kb0 = kt_ * 32;                                               \
      /* causal mask, permuted k = kb0 + quad*8 + 4*h2 + r */                 \
      _Pragma("unroll") for (int h2 = 0; h2 < 2; ++h2) {                      \
        if (kb0 + 27 + h2 * 4 > qbase) {                                      \
          int kb2 = kb0 + quad * 8 + h2 * 4;                                  \
          _Pragma("unroll") for (int r = 0; r < 4; ++r) {                     \
            if (kb2 + r > qgp) SCN[h2][r] = NEG_INF;                          \
          }                                                                   \
        }                                                                     \
      }                                                                       \
    }                                                                         \
    if (gprev) SOFTPV(SCO);                                                   \
    gprev = gcur;                                                             \
    vprev = vcur; vcur = vstage; vstage = (vstage == 2) ? 0 : vstage + 1;     \
    __syncthreads(); /* drains vmcnt (tile kt+1 resident) + publishes */      \
  } while (0)

    for (int kt = 0; kt < nkt; kt += 2) {
      PIPE(kt, 0, scA, scB);
      PIPE(kt + 1, 1, scB, scA);
    }
    // pipe epilogue: tile nkt-1 (odd parity -> scB); vprev = (nkt-1)%3.
    if (gprev) SOFTPV(scB);
#undef PIPE
#undef SOFTPV

    // ---- epilogue: row sum via butterfly, redistribute inv to acc rows ----
    float s = lsum;
    s += swz_x16(s);
    s += bperm_f(a32, s);
    float linv = 1.0f / s;  // valid at every lane for row q=l15
    f32x4 inv;
#pragma unroll
    for (int r = 0; r < 4; ++r) inv[r] = bperm_f(rowa + (r << 2), linv);
#pragma unroll
    for (int dt = 0; dt < 8; ++dt)
#pragma unroll
      for (int r = 0; r < 4; ++r)
        outg[(size_t)(b * S_ + qbase + quad * 4 + r) * (H_ * D_) +
             h * D_ + dt * 16 + l15] = acc[dt][r] * inv[r];
  }
}

extern "C" void kernel_launch(void* const* d_in, const int* in_sizes, int n_in,
                              void* d_out, int out_size, void* d_ws,
                              size_t ws_size, hipStream_t stream) {
  const float* q = (const float*)d_in[0];
  const float* k = (const float*)d_in[1];
  const float* v = (const float*)d_in[2];
  float* out = (float*)d_out;
  unsigned short* kws = (unsigned short*)d_ws;               // 8 MB Kbf
  unsigned short* vtws = kws + (size_t)B_ * HKV_ * S_ * D_;  // 8 MB Vt

  prep_kernel<<<4096, 256, 0, stream>>>(k, v, kws, vtws);

  dim3 g2(16, B_ * H_);  // 1024 blocks; XCD-locality remap inside kernel
  attn_kernel<<<g2, 256, 0, stream>>>(q, kws, vtws, out);
}

// Round 13
// 219.424 us; speedup vs baseline: 1.0379x; 1.0379x over previous
//
#include <hip/hip_runtime.h>

// Causal GQA prefill attention, flash-style, bf16 MFMA / fp32 softmax.
// B=2, S=2048, H=32, HKV=8, D=128, G=4.
// Prepass (fused, 1 launch): K fp32->bf16 [b][hkv][S][D] and V -> Vt.
// Round 11 = session best (attn 114 us, total 223.0): in-register P via
//   k-row-permuted staging, (256,4), 32 KB LDS, XCD remap, defer-max.
// Round 12 (T15 att[2] pipeline) regressed via reg spills (+11 MB FETCH
//   and WRITE) — third confirmation that the 128-reg budget has ZERO
//   slack: any added live state spills and loses more than it gains.
// Round 13: revert to round 11 verbatim.

#define B_   2
#define S_   2048
#define H_   32
#define HKV_ 8
#define D_   128
#define SCALEF 0.08838834764831845f
#define COEF  (SCALEF * 1.44269504088896340736f)   // scale * log2(e)
#define DEFER_THR 8.0f                             // log2-domain defer-max

typedef float          f32x4 __attribute__((ext_vector_type(4)));
typedef __bf16         bf16x4 __attribute__((ext_vector_type(4)));
typedef __bf16         bf16x8 __attribute__((ext_vector_type(8)));
typedef unsigned short u16x8 __attribute__((ext_vector_type(8)));

#define MFMA16(a, b, c) __builtin_amdgcn_mfma_f32_16x16x32_bf16((a), (b), (c), 0, 0, 0)

#if defined(__has_builtin)
#if __has_builtin(__builtin_amdgcn_exp2f)
#define EXP2F(x) __builtin_amdgcn_exp2f(x)
#endif
#endif
#ifndef EXP2F
#define EXP2F(x) exp2f(x)
#endif

static __device__ __forceinline__ unsigned short f2bf(float f) {
  unsigned int u = __builtin_bit_cast(unsigned int, f);
  u = (u + 0x7fffu + ((u >> 16) & 1u)) >> 16;   // RNE; inputs finite
  return (unsigned short)u;
}

// async global->LDS, 16B per lane; lds dest = wave-uniform base + lane*16.
static __device__ __forceinline__ void load_lds16(const void* g, void* l) {
  __builtin_amdgcn_global_load_lds(
      (const __attribute__((address_space(1))) void*)g,
      (__attribute__((address_space(3))) void*)l, 16, 0, 0);
}

// lane^16 exchange (DS pipe, within 32-lane halves): BitMode xor=16.
static __device__ __forceinline__ float swz_x16(float v) {
  return __builtin_bit_cast(
      float, __builtin_amdgcn_ds_swizzle(__builtin_bit_cast(int, v), 0x401F));
}
// generic pull from lane (byteaddr/4): full 64-lane crossbar.
static __device__ __forceinline__ float bperm_f(int byteaddr, float v) {
  return __builtin_bit_cast(
      float,
      __builtin_amdgcn_ds_bpermute(byteaddr, __builtin_bit_cast(int, v)));
}

// ------------- Fused prepass: blocks 0..2047 convert K, 2048..4095
// transpose V. Independent work -> concurrent, one launch. -------------
__global__ __launch_bounds__(256) void prep_kernel(
    const float* __restrict__ k, const float* __restrict__ v,
    unsigned short* __restrict__ kbf, unsigned short* __restrict__ vt) {
  __shared__ float tile[32][65];  // +1 pad: conflict-free (V branch only)
  const int tid = threadIdx.x;
  const int gid = (int)blockIdx.x;
  if (gid < 2048) {
    // ---- K fp32 -> bf16 [b][hkv][S][D] ----
    int t = gid * 256 + tid;
    int o = t * 8;                       // output-linear index
    int d = o & (D_ - 1);
    int s = (o >> 7) & (S_ - 1);
    int bh = o >> 18;                    // 0..15
    int b = bh >> 3, hkv = bh & 7;
    const float* src = k + (size_t)(b * S_ + s) * (HKV_ * D_) + hkv * D_ + d;
    f32x4 x0 = *(const f32x4*)src;
    f32x4 x1 = *(const f32x4*)(src + 4);
    u16x8 w;
    w[0] = f2bf(x0[0]); w[1] = f2bf(x0[1]); w[2] = f2bf(x0[2]); w[3] = f2bf(x0[3]);
    w[4] = f2bf(x1[0]); w[5] = f2bf(x1[1]); w[6] = f2bf(x1[2]); w[7] = f2bf(x1[3]);
    *(u16x8*)(kbf + o) = w;
  } else {
    // ---- V -> Vt (bf16, [b][hkv][D][S]) ----
    const int t = gid - 2048;
    const int s0 = (t & 31) * 64;        // 32 s-tiles
    const int d0 = ((t >> 5) & 3) * 32;  // 4 d-tiles
    const int bh = t >> 7;               // 16 (b*8+hkv)
    const float* src = v + (size_t)(bh >> 3) * S_ * (HKV_ * D_) + (bh & 7) * D_;
#pragma unroll
    for (int it = 0; it < 8; ++it) {
      int idx = it * 256 + tid;
      int sl = idx >> 5, dl = idx & 31;  // coalesced along d
      tile[dl][sl] = src[(size_t)(s0 + sl) * (HKV_ * D_) + d0 + dl];
    }
    __syncthreads();
    unsigned int* dst = (unsigned int*)vt;
#pragma unroll
    for (int it = 0; it < 4; ++it) {
      int idx = it * 256 + tid;
      int dl = idx >> 5, sp = idx & 31;
      unsigned int w = (unsigned int)f2bf(tile[dl][2 * sp]) |
                       ((unsigned int)f2bf(tile[dl][2 * sp + 1]) << 16);
      dst[(((size_t)bh * D_ + d0 + dl) * S_ + s0 + 2 * sp) >> 1] = w;
    }
  }
}

// ------------- Main attention kernel -------------
__global__ __launch_bounds__(256, 4) void attn_kernel(
    const float* __restrict__ qg, const unsigned short* __restrict__ kbfg,
    const unsigned short* __restrict__ vtg, float* __restrict__ outg) {
  __shared__ unsigned short KL[2][32 * 128];   // 2 x 8 KB (k-row permuted)
  __shared__ unsigned short VL[2][128 * 32];   // 2 x 8 KB (chunk-swizzled)
  // total LDS = 32768 B -> 4 blocks/CU at the 128-reg budget

  const int tid = threadIdx.x;
  const int wave = tid >> 6, lane = tid & 63;
  const int l15 = lane & 15, quad = lane >> 4;
  const int a32 = ((lane ^ 32) << 2);  // bpermute addr: lane+-32 partner
  const int rowa = quad << 4;          // bpermute addr base: row quad*4

  // XCD-locality remap: dispatch id round-robins xcd = id&7 (8 XCDs).
  const int id = (int)blockIdx.x + 16 * (int)blockIdx.y;  // 0..1023
  const int xcd = id & 7, slot = id >> 3;                 // slot 0..127
  const int bhkv = xcd * 2 + (slot >> 6);
  const int inner = slot & 63;
  const int g = inner >> 4;         // 0..3 head-in-group
  const int xb = inner & 15;        // causal pair index
  const int b = bhkv >> 3, hkv = bhkv & 7;
  const int h = hkv * 4 + g;

  const unsigned short* kbf = kbfg + (size_t)(b * HKV_ + hkv) * S_ * D_;
  const unsigned short* vtb = vtg + (size_t)(b * HKV_ + hkv) * D_ * S_;

  const f32x4 zero4 = {0.f, 0.f, 0.f, 0.f};
  const float NEG_INF = -__builtin_huge_valf();

  // ---- async staging of one K/Vt tile pair into buffer `buf` ----
  // K ROW PERMUTATION: LDS row kr = h2*16+i holds global k-row
  //   gs = (i>>2)*8 + h2*4 + (i&3)  (makes P lane-local for PV).
  // K chunk swizzle: phys chunk pc of row kr holds logical pc^(kr&15).
  // V chunk swizzle: phys chunk pc of row dr holds logical pc^((dr>>1)&3).
  auto stage = [&](int kt, int buf) {
#pragma unroll
    for (int j = 0; j < 2; ++j) {
      int si = wave * 128 + j * 64 + lane;
      int kr = si >> 4, pc = si & 15;
      int lc = pc ^ (kr & 15);
      int gs = ((kr & 15) >> 2) * 8 + ((kr >> 4) << 2) + (kr & 3);
      load_lds16(kbf + (size_t)(kt * 32 + gs) * D_ + lc * 8,
                 &KL[buf][(wave * 128 + j * 64) * 8]);
    }
#pragma unroll
    for (int j = 0; j < 2; ++j) {
      int si = wave * 128 + j * 64 + lane;
      int dr = si >> 2, pc = si & 3;
      int lc = pc ^ ((dr >> 1) & 3);
      load_lds16(vtb + (size_t)dr * S_ + kt * 32 + lc * 8,
                 &VL[buf][(wave * 128 + j * 64) * 8]);
    }
  };

  for (int ph = 0; ph < 2; ++ph) {
    const int qb = ph ? (31 - xb) : xb;
    const int qbase = qb * 64 + wave * 16;  // this wave's 16 q rows
    const int qgp = qbase + l15;            // this lane's q-row (swapped C)

    // Q fragments (A/B-layout identical), pre-scaled by COEF.
    bf16x8 qf[4];
#pragma unroll
    for (int ch = 0; ch < 4; ++ch) {
      const float* p = qg + (size_t)(b * S_ + qbase + l15) * (H_ * D_) +
                       h * D_ + ch * 32 + quad * 8;
      f32x4 x0 = *(const f32x4*)p;
      f32x4 x1 = *(const f32x4*)(p + 4);
      bf16x8 t;
      t[0] = (__bf16)(x0[0] * COEF); t[1] = (__bf16)(x0[1] * COEF);
      t[2] = (__bf16)(x0[2] * COEF); t[3] = (__bf16)(x0[3] * COEF);
      t[4] = (__bf16)(x1[0] * COEF); t[5] = (__bf16)(x1[1] * COEF);
      t[6] = (__bf16)(x1[2] * COEF); t[7] = (__bf16)(x1[3] * COEF);
      qf[ch] = t;
    }

    f32x4 acc[8];
#pragma unroll
    for (int dt = 0; dt < 8; ++dt) acc[dt] = zero4;
    float mrow = NEG_INF;  // running max of row q=l15 (scalar)
    float lsum = 0.f;      // lane-partial sum of row q=l15 over own k-cols

    const int nkt = qb * 2 + 2;  // always even

    stage(0, 0);
    __syncthreads();  // drains vmcnt: tile 0 resident

    // One k-tile body; CUR literal so KL/VL bases are compile-time offsets.
    // With permuted K rows: sc[h2][r] = S[k = kb0+quad*8+4*h2+r][q = l15]
    // -> lane holds exactly its PV A-fragment (k = quad*8 + 0..7).
#define KITER(KT, CUR)                                                        \
  do {                                                                        \
    const int kt_ = (KT);                                                     \
    if (kt_ + 1 < nkt) stage(kt_ + 1, (CUR) ^ 1);                             \
    if (kt_ * 32 <= qbase + 15) {                                             \
      f32x4 sc[2] = {zero4, zero4};                                           \
      __builtin_amdgcn_s_setprio(1);                                          \
      _Pragma("unroll") for (int h2 = 0; h2 < 2; ++h2) {                      \
        const int row = h2 * 16 + l15;                                        \
        _Pragma("unroll") for (int ch = 0; ch < 4; ++ch) {                    \
          const int pc = (ch * 4 + quad) ^ l15; /* un-swizzle */              \
          u16x8 kf = *(const u16x8*)&KL[(CUR)][row * D_ + pc * 8];            \
          sc[h2] = MFMA16(__builtin_bit_cast(bf16x8, kf), qf[ch], sc[h2]);    \
        }                                                                     \
      }                                                                       \
      __builtin_amdgcn_s_setprio(0);                                          \
      const int kb0 = kt_ * 32;                                               \
      /* causal mask, permuted k = kb0 + quad*8 + 4*h2 + r */                 \
      _Pragma("unroll") for (int h2 = 0; h2 < 2; ++h2) {                      \
        if (kb0 + 27 + h2 * 4 > qbase) {                                      \
          int kb2 = kb0 + quad * 8 + h2 * 4;                                  \
          _Pragma("unroll") for (int r = 0; r < 4; ++r) {                     \
            if (kb2 + r > qgp) sc[h2][r] = NEG_INF;                           \
          }                                                                   \
        }                                                                     \
      }                                                                       \
      /* defer-max (T13): lane's 8 scores are all row q=l15 */                \
      float l8 = fmaxf(fmaxf(fmaxf(sc[0][0], sc[0][1]),                       \
                             fmaxf(sc[0][2], sc[0][3])),                      \
                       fmaxf(fmaxf(sc[1][0], sc[1][1]),                       \
                             fmaxf(sc[1][2], sc[1][3])));                     \
      if (!__all(l8 <= mrow + DEFER_THR)) {                                   \
        float t = fmaxf(l8, swz_x16(l8));  /* cross-quad row max */           \
        t = fmaxf(t, bperm_f(a32, t));                                        \
        float mn = fmaxf(mrow, t);                                            \
        float al = EXP2F(mrow - mn);                                          \
        mrow = mn;                                                            \
        lsum *= al;                                                           \
        f32x4 av; /* alpha for acc rows quad*4+r, from lanes r' = row */      \
        _Pragma("unroll") for (int r = 0; r < 4; ++r)                         \
            av[r] = bperm_f(rowa + (r << 2), al);                             \
        _Pragma("unroll") for (int dt = 0; dt < 8; ++dt)                      \
            _Pragma("unroll") for (int r = 0; r < 4; ++r)                     \
                acc[dt][r] *= av[r];                                          \
      }                                                                       \
      /* shared P computation (P bounded by 2^THR = 256) */                   \
      _Pragma("unroll") for (int h2 = 0; h2 < 2; ++h2)                        \
          _Pragma("unroll") for (int r = 0; r < 4; ++r)                       \
              sc[h2][r] = EXP2F(sc[h2][r] - mrow);                            \
      lsum += ((sc[0][0] + sc[0][1]) + (sc[0][2] + sc[0][3])) +               \
              ((sc[1][0] + sc[1][1]) + (sc[1][2] + sc[1][3]));                \
      /* P -> PV A-fragment: pure register casts (v_cvt_pk_bf16_f32) */       \
      bf16x8 pb;                                                              \
      pb[0] = (__bf16)sc[0][0]; pb[1] = (__bf16)sc[0][1];                     \
      pb[2] = (__bf16)sc[0][2]; pb[3] = (__bf16)sc[0][3];                     \
      pb[4] = (__bf16)sc[1][0]; pb[5] = (__bf16)sc[1][1];                     \
      pb[6] = (__bf16)sc[1][2]; pb[7] = (__bf16)sc[1][3];                     \
      /* PV: A = P (in-register), B = Vt (swizzled chunks) */                 \
      {                                                                       \
        const int vsw = (quad ^ ((l15 >> 1) & 3)) * 8;                        \
        __builtin_amdgcn_s_setprio(1);                                        \
        _Pragma("unroll") for (int dt = 0; dt < 8; ++dt) {                    \
          u16x8 vf = *(const u16x8*)&VL[(CUR)][(dt * 16 + l15) * 32 + vsw];   \
          acc[dt] = MFMA16(pb, __builtin_bit_cast(bf16x8, vf), acc[dt]);      \
        }                                                                     \
        __builtin_amdgcn_s_setprio(0);                                        \
      }                                                                       \
    }                                                                         \
    __syncthreads(); /* drains vmcnt (next tile resident) + publishes bufs */ \
  } while (0)

    for (int kt = 0; kt < nkt; kt += 2) {
      KITER(kt, 0);
      KITER(kt + 1, 1);
    }
#undef KITER

    // ---- epilogue: row sum via butterfly, redistribute inv to acc rows ----
    float s = lsum;
    s += swz_x16(s);
    s += bperm_f(a32, s);
    float linv = 1.0f / s;  // valid at every lane for row q=l15
    f32x4 inv;
#pragma unroll
    for (int r = 0; r < 4; ++r) inv[r] = bperm_f(rowa + (r << 2), linv);
#pragma unroll
    for (int dt = 0; dt < 8; ++dt)
#pragma unroll
      for (int r = 0; r < 4; ++r)
        outg[(size_t)(b * S_ + qbase + quad * 4 + r) * (H_ * D_) +
             h * D_ + dt * 16 + l15] = acc[dt][r] * inv[r];
  }
}

extern "C" void kernel_launch(void* const* d_in, const int* in_sizes, int n_in,
                              void* d_out, int out_size, void* d_ws,
                              size_t ws_size, hipStream_t stream) {
  const float* q = (const float*)d_in[0];
  const float* k = (const float*)d_in[1];
  const float* v = (const float*)d_in[2];
  float* out = (float*)d_out;
  unsigned short* kws = (unsigned short*)d_ws;               // 8 MB Kbf
  unsigned short* vtws = kws + (size_t)B_ * HKV_ * S_ * D_;  // 8 MB Vt

  prep_kernel<<<4096, 256, 0, stream>>>(k, v, kws, vtws);

  dim3 g2(16, B_ * H_);  // 1024 blocks; XCD-locality remap inside kernel
  attn_kernel<<<g2, 256, 0, stream>>>(q, kws, vtws, out);
}